// Round 5
// baseline (81.262 us; speedup 1.0000x reference)
//
#include <hip/hip_runtime.h>
#include <math.h>

#define N_TOK 8192
#define DIM   1024
#define NE    8
#define NR    16
#define NO    3072
#define OUT_ELEMS (N_TOK * NO)   // 25165824

__device__ __forceinline__ float softplusf(float z) {
  return z > 0.f ? z + log1pf(expf(-z)) : log1pf(expf(z));
}
__device__ __forceinline__ float ncdf(float z) {
  return 0.5f * erfcf(-z * 0.70710678118654752f);
}

#define FMA4(A, S, W) { (A).x = fmaf((S),(W).x,(A).x); (A).y = fmaf((S),(W).y,(A).y); \
                        (A).z = fmaf((S),(W).z,(A).z); (A).w = fmaf((S),(W).w,(A).w); }
#define DOT4ACC(ACC, X, W) ACC = fmaf((X).x,(W).x, fmaf((X).y,(W).y, fmaf((X).z,(W).z, fmaf((X).w,(W).w,(ACC)))))
#define Z4 make_float4(0.f,0.f,0.f,0.f)

typedef __attribute__((address_space(3))) void LDSV;
typedef const __attribute__((address_space(1))) void GLBV;
__device__ __forceinline__ void stage16(const void* g, void* l) {
  __builtin_amdgcn_global_load_lds((GLBV*)g, (LDSV*)l, 16, 0, 0);
}
__device__ __forceinline__ void waitvm0() {
  asm volatile("s_waitcnt vmcnt(0)" ::: "memory");
}

#define KA_SMEM (65536 + 32768 + 20480)          // wl + xl(2 buf) + lgP
#define KD_SMEM (65536 + 32768 + 20480 + 128)    // la + xl(2 buf) + hP + toks

// ---------------------------------------------------------------------------
// Kernel A: gating GEMV, streaming form. 32 tokens/block, 512 threads.
// w (both mats, 64 KB) -> LDS via global_load_lds; x in 16 KB dbuf chunks.
// Thread = (tok = t&31, oh = out-half, dh = d-eighth); acc = 8 outs over 128 d.
// x rows rotation-swizzled by tok to spread LDS bank sweeps (pre-swizzled src).
// ---------------------------------------------------------------------------
__global__ __launch_bounds__(512) void kA(const float* __restrict__ x,
    const float* __restrict__ wg, const float* __restrict__ wn,
    const float* __restrict__ nz, int* __restrict__ eid, float* __restrict__ part) {
  extern __shared__ char smem[];
  float4* wl  = (float4*)smem;                    // [1024 d][4 cols]
  float4* xl  = (float4*)(smem + 65536);          // [2][32 tok][32 col4]
  float*  lgP = (float*)(smem + 65536 + 32768);   // [8 dh][32 tok][20]
  int t = threadIdx.x;
  int n0 = blockIdx.x << 5;
  // ---- stage weights: slot s = d*4 + c; c: 0,1 = wg cols 0-3/4-7; 2,3 = wn
  #pragma unroll
  for (int j = 0; j < 8; ++j) {
    int s = t + (j << 9);
    int d = s >> 2, c = s & 3;
    const float* src = (c < 2 ? wg : wn) + d * NE + ((c & 1) << 2);
    stage16(src, wl + s);
  }
  // ---- x chunk staging setup (2 slots/thread), pre-swizzled global source
  int f1 = t, f2 = t + 512;
  int tk1 = f1 >> 5, cl1 = ((f1 & 31) - tk1) & 31;
  int tk2 = f2 >> 5, cl2 = ((f2 & 31) - tk2) & 31;
  const float* xs1 = x + (size_t)(n0 + tk1) * DIM + ((cl1 >> 2) << 7) + ((cl1 & 3) << 2);
  const float* xs2 = x + (size_t)(n0 + tk2) * DIM + ((cl2 >> 2) << 7) + ((cl2 & 3) << 2);
  stage16(xs1, xl + f1);
  stage16(xs2, xl + f2);
  waitvm0();
  __syncthreads();
  // ---- compute
  int tok = t & 31, oh = (t >> 5) & 1, dh = t >> 6;
  int oh2 = oh << 1;
  float4 accA = Z4, accB = Z4;
  for (int c = 0; c < 8; ++c) {
    int buf = (c & 1) << 10;
    if (c < 7) {
      int nb = ((c + 1) & 1) << 10;
      stage16(xs1 + ((c + 1) << 4), xl + nb + f1);
      stage16(xs2 + ((c + 1) << 4), xl + nb + f2);
    }
    #pragma unroll
    for (int i4 = 0; i4 < 4; ++i4) {
      float4 xv = xl[buf + (tok << 5) + (((dh << 2) + i4 + tok) & 31)];
      int d0 = (dh << 7) + (c << 4) + (i4 << 2);
      float4 wA0 = wl[((d0 + 0) << 2) + oh2], wB0 = wl[((d0 + 0) << 2) + oh2 + 1];
      float4 wA1 = wl[((d0 + 1) << 2) + oh2], wB1 = wl[((d0 + 1) << 2) + oh2 + 1];
      float4 wA2 = wl[((d0 + 2) << 2) + oh2], wB2 = wl[((d0 + 2) << 2) + oh2 + 1];
      float4 wA3 = wl[((d0 + 3) << 2) + oh2], wB3 = wl[((d0 + 3) << 2) + oh2 + 1];
      FMA4(accA, xv.x, wA0); FMA4(accB, xv.x, wB0);
      FMA4(accA, xv.y, wA1); FMA4(accB, xv.y, wB1);
      FMA4(accA, xv.z, wA2); FMA4(accB, xv.z, wB2);
      FMA4(accA, xv.w, wA3); FMA4(accB, xv.w, wB3);
    }
    waitvm0();
    __syncthreads();
  }
  // ---- combine d-eighths
  *(float4*)&lgP[(((dh << 5) + tok) * 20) + (oh << 3)]     = accA;
  *(float4*)&lgP[(((dh << 5) + tok) * 20) + (oh << 3) + 4] = accB;
  __syncthreads();
  if (t < 32) {
    int n = n0 + t;
    float lg16[16];
    #pragma unroll
    for (int o4 = 0; o4 < 4; ++o4) {
      float4 s = Z4;
      #pragma unroll
      for (int d8 = 0; d8 < 8; ++d8) {
        float4 v = *(const float4*)&lgP[(((d8 << 5) + t) * 20) + (o4 << 2)];
        s.x += v.x; s.y += v.y; s.z += v.z; s.w += v.w;
      }
      lg16[o4 * 4 + 0] = s.x; lg16[o4 * 4 + 1] = s.y;
      lg16[o4 * 4 + 2] = s.z; lg16[o4 * 4 + 3] = s.w;
    }
    float cl[8], st[8], lg[8];
    #pragma unroll
    for (int e = 0; e < 8; ++e) cl[e] = lg16[e];
    #pragma unroll
    for (int e = 0; e < 8; ++e) {
      st[e] = softplusf(lg16[8 + e]) + 0.01f;
      lg[e] = fmaf(nz[(size_t)n * NE + e], st[e], cl[e]);
    }
    float m1 = -1e30f, m2 = -1e30f; int idx = 0;
    #pragma unroll
    for (int e = 0; e < 8; ++e) {
      float v = lg[e];
      if (v > m1)      { m2 = m1; m1 = v; idx = e; }
      else if (v > m2) { m2 = v; }
    }
    eid[n] = idx;
    float pr[8], cw[8];
    #pragma unroll
    for (int e = 0; e < 8; ++e) {
      float thr = (lg[e] > m2) ? m2 : m1;
      pr[e] = ncdf((cl[e] - thr) / st[e]);
    }
    #pragma unroll
    for (int e = 0; e < 8; ++e) cw[e] = (float)__popcll(__ballot(idx == e));
    #pragma unroll
    for (int e = 0; e < 8; ++e) {
      #pragma unroll
      for (int off = 1; off <= 16; off <<= 1) pr[e] += __shfl_xor(pr[e], off);
    }
    if (t == 0) {
      #pragma unroll
      for (int e = 0; e < 8; ++e) {
        part[blockIdx.x * 16 + e]     = cw[e];
        part[blockIdx.x * 16 + 8 + e] = pr[e];
      }
    }
  }
}

// ---------------------------------------------------------------------------
// Kernel B: reduce 256x16 partials -> importance[8], load[8]; counts; fill=0.
// ---------------------------------------------------------------------------
__global__ __launch_bounds__(256) void kB(const float* __restrict__ part,
    float* __restrict__ outIL, int* __restrict__ counts, int* __restrict__ fill) {
  __shared__ float red[16][16];
  int t = threadIdx.x;
  int s = t & 15, g = t >> 4;
  float sum = 0.f;
  #pragma unroll
  for (int j = 0; j < 16; ++j) sum += part[(g + 16 * j) * 16 + s];
  red[g][s] = sum;
  __syncthreads();
  if (t < 16) {
    float tot = 0.f;
    #pragma unroll
    for (int gg = 0; gg < 16; ++gg) tot += red[gg][t];
    outIL[t] = tot;
    if (t < 8) { counts[t] = (int)(tot + 0.5f); fill[t] = 0; }
  }
}

// ---------------------------------------------------------------------------
// Kernel C: bucket tokens by expert (LDS hist + 8 global atomics per block).
// ---------------------------------------------------------------------------
__global__ __launch_bounds__(256) void kC(const int* __restrict__ eid,
    const int* __restrict__ counts, int* __restrict__ fill, int* __restrict__ bucket) {
  __shared__ int lcnt[8], lbase[8];
  int t = threadIdx.x;
  if (t < 8) lcnt[t] = 0;
  __syncthreads();
  int n = blockIdx.x * 256 + t;
  int e = eid[n];
  int rank = atomicAdd(&lcnt[e], 1);
  __syncthreads();
  if (t < 8) lbase[t] = atomicAdd(&fill[t], lcnt[t]);
  __syncthreads();
  int off = 0;
  #pragma unroll
  for (int i = 0; i < 8; ++i) if (i < e) off += counts[i];
  bucket[off + lbase[e] + rank] = n;
}

// ---------------------------------------------------------------------------
// Kernel D: h_sorted[p] = lora_a[e] @ x[bucket[p]], 32 tokens/tile, streaming.
// la[e] (64 KB, [16 r][1024 d]) -> LDS; x gathered rows in dbuf chunks.
// Thread = (tok, rh = r-half, dh = d-eighth); acc = 8 r over 128 d.
// ---------------------------------------------------------------------------
__global__ __launch_bounds__(512) void kD(const float* __restrict__ x,
    const float* __restrict__ la, const int* __restrict__ counts,
    const int* __restrict__ bucket, float* __restrict__ h) {
  extern __shared__ char smem[];
  float*  lal  = (float*)smem;                    // [16 r][1024 d]
  float4* lal4 = (float4*)smem;
  float4* xl   = (float4*)(smem + 65536);         // [2][32 tok][32 col4]
  float*  hP   = (float*)(smem + 65536 + 32768);  // [8 dh][32 tok][20]
  int*    toks = (int*)(smem + 65536 + 32768 + 20480);
  int tile = blockIdx.x;
  int e = -1, jt = 0, off = 0;
  { int tot = 0, o = 0;
    #pragma unroll
    for (int i = 0; i < 8; ++i) {
      int c = counts[i]; int nt = (c + 31) >> 5;
      if (e < 0 && tile < tot + nt) { e = i; jt = tile - tot; off = o; }
      tot += nt; o += c;
    } }
  if (e < 0) return;
  int cnt = counts[e];
  int p0 = off + (jt << 5);
  int valid = min(32, cnt - (jt << 5));
  int t = threadIdx.x;
  if (t < 32) toks[t] = bucket[p0 + min(t, valid - 1)];
  // stage la while toks settles (la doesn't need toks)
  #pragma unroll
  for (int j = 0; j < 8; ++j) {
    int s = t + (j << 9);
    stage16(la + (size_t)e * (NR * DIM) + ((size_t)s << 2), lal4 + s);
  }
  __syncthreads();   // toks visible
  int f1 = t, f2 = t + 512;
  int tk1 = f1 >> 5, cl1 = ((f1 & 31) - tk1) & 31;
  int tk2 = f2 >> 5, cl2 = ((f2 & 31) - tk2) & 31;
  const float* xs1 = x + (size_t)toks[tk1] * DIM + ((cl1 >> 2) << 7) + ((cl1 & 3) << 2);
  const float* xs2 = x + (size_t)toks[tk2] * DIM + ((cl2 >> 2) << 7) + ((cl2 & 3) << 2);
  stage16(xs1, xl + f1);
  stage16(xs2, xl + f2);
  waitvm0();
  __syncthreads();
  int tok = t & 31, rh = (t >> 5) & 1, dh = t >> 6;
  int rb = rh << 3;
  float4 accA = Z4, accB = Z4;
  for (int c = 0; c < 8; ++c) {
    int buf = (c & 1) << 10;
    if (c < 7) {
      int nb = ((c + 1) & 1) << 10;
      stage16(xs1 + ((c + 1) << 4), xl + nb + f1);
      stage16(xs2 + ((c + 1) << 4), xl + nb + f2);
    }
    #pragma unroll
    for (int i4 = 0; i4 < 4; ++i4) {
      float4 xv = xl[buf + (tok << 5) + (((dh << 2) + i4 + tok) & 31)];
      int d0 = (dh << 7) + (c << 4) + (i4 << 2);
      float4 a0 = *(const float4*)(lal + (rb + 0) * DIM + d0);
      float4 a1 = *(const float4*)(lal + (rb + 1) * DIM + d0);
      float4 a2 = *(const float4*)(lal + (rb + 2) * DIM + d0);
      float4 a3 = *(const float4*)(lal + (rb + 3) * DIM + d0);
      float4 a4 = *(const float4*)(lal + (rb + 4) * DIM + d0);
      float4 a5 = *(const float4*)(lal + (rb + 5) * DIM + d0);
      float4 a6 = *(const float4*)(lal + (rb + 6) * DIM + d0);
      float4 a7 = *(const float4*)(lal + (rb + 7) * DIM + d0);
      DOT4ACC(accA.x, xv, a0); DOT4ACC(accA.y, xv, a1);
      DOT4ACC(accA.z, xv, a2); DOT4ACC(accA.w, xv, a3);
      DOT4ACC(accB.x, xv, a4); DOT4ACC(accB.y, xv, a5);
      DOT4ACC(accB.z, xv, a6); DOT4ACC(accB.w, xv, a7);
    }
    waitvm0();
    __syncthreads();
  }
  *(float4*)&hP[(((dh << 5) + tok) * 20) + rb]     = accA;
  *(float4*)&hP[(((dh << 5) + tok) * 20) + rb + 4] = accB;
  __syncthreads();
  if (t < 128) {
    int tk = t >> 2, cc = t & 3;
    if (tk < valid) {
      float4 s = Z4;
      #pragma unroll
      for (int d8 = 0; d8 < 8; ++d8) {
        float4 v = *(const float4*)&hP[(((d8 << 5) + tk) * 20) + (cc << 2)];
        s.x += v.x; s.y += v.y; s.z += v.z; s.w += v.w;
      }
      *(float4*)(h + (size_t)(p0 + tk) * NR + (cc << 2)) = s;
    }
  }
}

// ---------------------------------------------------------------------------
// Kernel E: out[n] = lora_b[e] @ h. Tiles: 64 tokens x 256 outs.
// ---------------------------------------------------------------------------
__global__ __launch_bounds__(256) void kE(const float* __restrict__ h,
    const float* __restrict__ lb, const int* __restrict__ counts,
    const int* __restrict__ bucket, float* __restrict__ out) {
  __shared__ float bt[16][260];
  __shared__ float ht[16][64];
  __shared__ int toks[64];
  int tile = blockIdx.y;
  int e = -1, jt = 0, off = 0;
  { int tot = 0, o = 0;
    #pragma unroll
    for (int i = 0; i < 8; ++i) {
      int c = counts[i]; int nt = (c + 63) >> 6;
      if (e < 0 && tile < tot + nt) { e = i; jt = tile - tot; off = o; }
      tot += nt; o += c;
    } }
  if (e < 0) return;
  int cnt = counts[e];
  int p0 = off + (jt << 6);
  int valid = min(64, cnt - (jt << 6));
  int o0 = blockIdx.x << 8;
  int t = threadIdx.x;
  if (t < 64) toks[t] = bucket[p0 + min(t, valid - 1)];
  const float* bbase = lb + ((size_t)e * NO + o0) * NR;
  #pragma unroll
  for (int kk = 0; kk < 4; ++kk) {
    int idx = (kk << 8) + t;
    int o = idx >> 2, rq = (idx & 3) << 2;
    float4 v = *(const float4*)(bbase + o * NR + rq);
    bt[rq + 0][o] = v.x; bt[rq + 1][o] = v.y; bt[rq + 2][o] = v.z; bt[rq + 3][o] = v.w;
  }
  { int tok = t >> 2, rq = (t & 3) << 2;
    float4 v = *(const float4*)(h + (size_t)(p0 + min(tok, valid - 1)) * NR + rq);
    ht[rq + 0][tok] = v.x; ht[rq + 1][tok] = v.y; ht[rq + 2][tok] = v.z; ht[rq + 3][tok] = v.w; }
  __syncthreads();
  int og = t & 31, tokg = t >> 5;
  int ob = og << 2, tb = tokg << 3;
  float4 z = Z4;
  float4 aL0=z,aL1=z,aL2=z,aL3=z,aL4=z,aL5=z,aL6=z,aL7=z;
  float4 aH0=z,aH1=z,aH2=z,aH3=z,aH4=z,aH5=z,aH6=z,aH7=z;
  #pragma unroll
  for (int r = 0; r < 16; ++r) {
    float4 blo = *(const float4*)&bt[r][ob];
    float4 bhi = *(const float4*)&bt[r][ob + 128];
    float4 h0  = *(const float4*)&ht[r][tb];
    float4 h1  = *(const float4*)&ht[r][tb + 4];
    FMA4(aL0, h0.x, blo); FMA4(aH0, h0.x, bhi);
    FMA4(aL1, h0.y, blo); FMA4(aH1, h0.y, bhi);
    FMA4(aL2, h0.z, blo); FMA4(aH2, h0.z, bhi);
    FMA4(aL3, h0.w, blo); FMA4(aH3, h0.w, bhi);
    FMA4(aL4, h1.x, blo); FMA4(aH4, h1.x, bhi);
    FMA4(aL5, h1.y, blo); FMA4(aH5, h1.y, bhi);
    FMA4(aL6, h1.z, blo); FMA4(aH6, h1.z, bhi);
    FMA4(aL7, h1.w, blo); FMA4(aH7, h1.w, bhi);
  }
  #define ST(J, AL, AH) { int tt = tb + (J); if (tt < valid) { \
      float* p = out + (size_t)toks[tt] * NO + o0 + ob; \
      *(float4*)p = AL; *(float4*)(p + 128) = AH; } }
  ST(0, aL0, aH0); ST(1, aL1, aH1); ST(2, aL2, aH2); ST(3, aL3, aH3);
  ST(4, aL4, aH4); ST(5, aL5, aH5); ST(6, aL6, aH6); ST(7, aL7, aH7);
  #undef ST
}

// ---------------------------------------------------------------------------
extern "C" void kernel_launch(void* const* d_in, const int* in_sizes, int n_in,
                              void* d_out, int out_size, void* d_ws, size_t ws_size,
                              hipStream_t stream) {
  const float* x  = (const float*)d_in[0];
  const float* wg = (const float*)d_in[1];
  const float* wn = (const float*)d_in[2];
  const float* la = (const float*)d_in[3];
  const float* lb = (const float*)d_in[4];
  const float* nz = (const float*)d_in[5];
  float* out = (float*)d_out;

  char* ws = (char*)d_ws;
  float* h        = (float*)(ws);                 // 524288 B
  int*   eid      = (int*)  (ws + 524288);        // 32768 B
  int*   bucket   = (int*)  (ws + 557056);        // 32768 B
  float* partials = (float*)(ws + 589824);        // 16384 B used
  int*   counts   = (int*)  (ws + 622592);        // 32 B
  int*   fill     = (int*)  (ws + 622624);        // 32 B

  hipFuncSetAttribute((const void*)kA, hipFuncAttributeMaxDynamicSharedMemorySize, KA_SMEM);
  hipFuncSetAttribute((const void*)kD, hipFuncAttributeMaxDynamicSharedMemorySize, KD_SMEM);

  kA<<<256, 512, KA_SMEM, stream>>>(x, wg, wn, nz, eid, partials);
  kB<<<1, 256, 0, stream>>>(partials, out + OUT_ELEMS, counts, fill);
  kC<<<32, 256, 0, stream>>>(eid, counts, fill, bucket);
  kD<<<263, 512, KD_SMEM, stream>>>(x, la, counts, bucket, h);
  kE<<<dim3(12, 135), 256, 0, stream>>>(h, lb, counts, bucket, out);
}